// Round 1
// baseline (331.057 us; speedup 1.0000x reference)
//
#include <hip/hip_runtime.h>

// Problem constants (from setup_inputs)
#define NB 8
#define NC 3
#define NT 32
#define NH 224
#define NW 224
#define DIFF 16
// enlarged: 240x240; inv_scale = in/out = 224/240
#define INV_SCALE (224.0f / 240.0f)

__global__ __launch_bounds__(256) void shake_crop_kernel(
    const float* __restrict__ video,
    const int* __restrict__ shake_h,
    const int* __restrict__ shake_w,
    float* __restrict__ out)
{
    const int W4 = NW / 4;                       // 56 float4 per row
    const int total4 = NB * NC * NT * NH * W4;   // 9,633,792
    int idx = blockIdx.x * blockDim.x + threadIdx.x;
    if (idx >= total4) return;

    // idx -> (bc, t, y, x4); output layout [B,C,T,H,W] contiguous
    int x4 = idx % W4;
    int r1 = idx / W4;
    int y  = r1 % NH;
    int r2 = r1 / NH;
    int t  = r2 % NT;
    int bc = r2 / NT;                            // b*C + c in [0,24)

    const float* frame = video + (size_t)(bc * NT + t) * (NH * NW);

    // Vertical taps (shared by the 4 outputs of this thread)
    int oy = y + shake_h[t];
    float iy = (oy + 0.5f) * INV_SCALE - 0.5f;
    iy = fminf(fmaxf(iy, 0.0f), (float)(NH - 1));   // clamp == jax renormalized edge
    int   y0 = (int)iy;                             // iy >= 0 -> trunc == floor
    float fy = iy - (float)y0;
    int   y1 = min(y0 + 1, NH - 1);
    const float* row0 = frame + y0 * NW;
    const float* row1 = frame + y1 * NW;

    int swt = shake_w[t];
    int xbase = x4 * 4 + swt;

    float4 res;
    float* rp = &res.x;
    #pragma unroll
    for (int j = 0; j < 4; ++j) {
        int ox = xbase + j;
        float ix = (ox + 0.5f) * INV_SCALE - 0.5f;
        ix = fminf(fmaxf(ix, 0.0f), (float)(NW - 1));
        int   x0 = (int)ix;
        float fx = ix - (float)x0;
        int   x1 = min(x0 + 1, NW - 1);

        float v00 = row0[x0];
        float v01 = row0[x1];
        float v10 = row1[x0];
        float v11 = row1[x1];

        float top = v00 + fx * (v01 - v00);
        float bot = v10 + fx * (v11 - v10);
        float v   = top + fy * (bot - top);
        rp[j] = fminf(fmaxf(v, 0.0f), 1.0f);    // clip(0,1)
    }

    ((float4*)out)[idx] = res;
}

extern "C" void kernel_launch(void* const* d_in, const int* in_sizes, int n_in,
                              void* d_out, int out_size, void* d_ws, size_t ws_size,
                              hipStream_t stream) {
    const float* video   = (const float*)d_in[0];
    const int*   shake_h = (const int*)d_in[1];
    const int*   shake_w = (const int*)d_in[2];
    float*       out     = (float*)d_out;

    const int total4 = NB * NC * NT * NH * (NW / 4);
    const int block  = 256;
    const int grid   = (total4 + block - 1) / block;
    shake_crop_kernel<<<grid, block, 0, stream>>>(video, shake_h, shake_w, out);
}

// Round 2
// 277.408 us; speedup vs baseline: 1.1934x; 1.1934x over previous
//
#include <hip/hip_runtime.h>

// Problem constants (from setup_inputs)
#define NB 8
#define NC 3
#define NT 32
#define NH 224
#define NW 224
#define DIFF 16
#define INV_SCALE (224.0f / 240.0f)   // in/out = 14/15

#define TILE_ROWS 32                  // output rows per block
#define MAX_LDS_ROWS 32               // input rows staged (needed <= 31)
#define TILES_PER_FRAME (NH / TILE_ROWS)   // 7
#define NFRAMES (NB * NC * NT)        // 768

__global__ __launch_bounds__(256) void shake_crop_lds_kernel(
    const float* __restrict__ video,
    const int* __restrict__ shake_h,
    const int* __restrict__ shake_w,
    float* __restrict__ out)
{
    __shared__ float lds[MAX_LDS_ROWS * NW];   // 28672 B

    const int tid  = threadIdx.x;
    const int f    = blockIdx.x / TILES_PER_FRAME;   // frame index (b*C+c)*T + t
    const int tile = blockIdx.x % TILES_PER_FRAME;
    const int t    = f % NT;
    const int ybase = tile * TILE_ROWS;

    const int sh = shake_h[t];
    const int sw = shake_w[t];

    // Input-row span needed for output rows ybase..ybase+31 (iy monotone in ry)
    float iy_first = fminf(fmaxf((ybase + sh + 0.5f) * INV_SCALE - 0.5f, 0.0f), (float)(NH - 1));
    float iy_last  = fminf(fmaxf((ybase + TILE_ROWS - 1 + sh + 0.5f) * INV_SCALE - 0.5f, 0.0f), (float)(NH - 1));
    const int r0    = (int)iy_first;                       // first needed input row
    const int r_end = min((int)iy_last + 1, NH - 1);       // last needed input row
    const int nrows = r_end - r0 + 1;                      // <= 31

    // Stage rows r0..r_end: ONE contiguous span -> coalesced float4 copy
    const float* frame = video + (size_t)f * (NH * NW);
    const float4* src4 = (const float4*)(frame + r0 * NW); // r0*224*4B is 16B-aligned
    float4* lds4 = (float4*)lds;
    const int n4 = nrows * (NW / 4);                       // <= 1736
    for (int j = tid; j < n4; j += 256)
        lds4[j] = src4[j];
    __syncthreads();

    // Compute 32x224 outputs; 1 scalar output per thread-iteration,
    // consecutive lanes = consecutive x -> coalesced stores, ~2-way LDS aliasing (free)
    float* obase = out + (size_t)f * (NH * NW) + ybase * NW;
    for (int i = tid; i < TILE_ROWS * NW; i += 256) {
        int ry = i / NW;
        int x  = i - ry * NW;

        float iy = fminf(fmaxf((ybase + ry + sh + 0.5f) * INV_SCALE - 0.5f, 0.0f), (float)(NH - 1));
        int   y0 = (int)iy;
        float fy = iy - (float)y0;
        int   y1 = min(y0 + 1, NH - 1);
        const float* row0 = lds + (y0 - r0) * NW;
        const float* row1 = lds + (y1 - r0) * NW;

        float ix = fminf(fmaxf((x + sw + 0.5f) * INV_SCALE - 0.5f, 0.0f), (float)(NW - 1));
        int   x0 = (int)ix;
        float fx = ix - (float)x0;
        int   x1 = min(x0 + 1, NW - 1);

        float v00 = row0[x0];
        float v01 = row0[x1];
        float v10 = row1[x0];
        float v11 = row1[x1];

        float top = v00 + fx * (v01 - v00);
        float bot = v10 + fx * (v11 - v10);
        float v   = top + fy * (bot - top);
        obase[ry * NW + x] = fminf(fmaxf(v, 0.0f), 1.0f);
    }
}

extern "C" void kernel_launch(void* const* d_in, const int* in_sizes, int n_in,
                              void* d_out, int out_size, void* d_ws, size_t ws_size,
                              hipStream_t stream) {
    const float* video   = (const float*)d_in[0];
    const int*   shake_h = (const int*)d_in[1];
    const int*   shake_w = (const int*)d_in[2];
    float*       out     = (float*)d_out;

    const int grid = NFRAMES * TILES_PER_FRAME;   // 5376 blocks
    shake_crop_lds_kernel<<<grid, 256, 0, stream>>>(video, shake_h, shake_w, out);
}

// Round 3
// 268.864 us; speedup vs baseline: 1.2313x; 1.0318x over previous
//
#include <hip/hip_runtime.h>

// Problem constants (from setup_inputs)
#define NB 8
#define NC 3
#define NT 32
#define NH 224
#define NW 224
#define DIFF 16
#define INV_SCALE (224.0f / 240.0f)   // in/out = 14/15

#define TILE_ROWS 16                  // output rows per block
#define LDS_ROWS 16                   // input rows staged (span of 16 out rows = <=16 in rows)
#define TILES_PER_FRAME (NH / TILE_ROWS)   // 14
#define NFRAMES (NB * NC * NT)        // 768

__global__ __launch_bounds__(256) void shake_crop_lds16_kernel(
    const float* __restrict__ video,
    const int* __restrict__ shake_h,
    const int* __restrict__ shake_w,
    float* __restrict__ out)
{
    __shared__ float lds[LDS_ROWS * NW];   // 14336 B -> 8 blocks/CU (100% waves)

    const int tid  = threadIdx.x;
    const int f    = blockIdx.x / TILES_PER_FRAME;   // frame index (b*C+c)*T + t
    const int tile = blockIdx.x % TILES_PER_FRAME;
    const int t    = f % NT;
    const int ybase = tile * TILE_ROWS;

    const int sh = shake_h[t];
    const int sw = shake_w[t];

    // Input-row span for output rows ybase..ybase+15 (iy monotone; span <= 16 rows)
    float iy_first = fminf(fmaxf((ybase + sh + 0.5f) * INV_SCALE - 0.5f, 0.0f), (float)(NH - 1));
    float iy_last  = fminf(fmaxf((ybase + TILE_ROWS - 1 + sh + 0.5f) * INV_SCALE - 0.5f, 0.0f), (float)(NH - 1));
    const int r0    = (int)iy_first;
    const int r_end = min((int)iy_last + 1, NH - 1);
    const int nrows = r_end - r0 + 1;                      // <= 16

    // Stage rows r0..r_end: one contiguous global span, coalesced float4 copy
    const float* frame = video + (size_t)f * (NH * NW);
    const float4* src4 = (const float4*)(frame + r0 * NW); // 224*4B rows stay 16B-aligned
    float4* lds4 = (float4*)lds;
    const int n4 = nrows * (NW / 4);                       // <= 896
    for (int j = tid; j < n4; j += 256)
        lds4[j] = src4[j];
    __syncthreads();

    // Compute: 4 consecutive outputs per thread-iteration (shared vertical taps),
    // float4 coalesced stores. 896 quads per tile.
    const int W4 = NW / 4;                                 // 56
    const int NQ = TILE_ROWS * W4;                         // 896
    float4* obase4 = (float4*)(out + (size_t)f * (NH * NW) + (size_t)ybase * NW);

    for (int i = tid; i < NQ; i += 256) {
        int ry = i / W4;
        int q  = i - ry * W4;

        float iy = fminf(fmaxf((ybase + ry + sh + 0.5f) * INV_SCALE - 0.5f, 0.0f), (float)(NH - 1));
        int   y0 = (int)iy;
        float fy = iy - (float)y0;
        int   y1 = min(y0 + 1, NH - 1);
        const float* row0 = lds + (y0 - r0) * NW;
        const float* row1 = lds + (y1 - r0) * NW;

        int xb = q * 4 + sw;
        float4 res;
        float* rp = &res.x;
        #pragma unroll
        for (int j = 0; j < 4; ++j) {
            int ox = xb + j;
            float ix = fminf(fmaxf((ox + 0.5f) * INV_SCALE - 0.5f, 0.0f), (float)(NW - 1));
            int   x0 = (int)ix;
            float fx = ix - (float)x0;
            int   x1 = min(x0 + 1, NW - 1);

            float v00 = row0[x0];
            float v01 = row0[x1];
            float v10 = row1[x0];
            float v11 = row1[x1];

            float top = v00 + fx * (v01 - v00);
            float bot = v10 + fx * (v11 - v10);
            float v   = top + fy * (bot - top);
            rp[j] = fminf(fmaxf(v, 0.0f), 1.0f);
        }
        obase4[i] = res;
    }
}

extern "C" void kernel_launch(void* const* d_in, const int* in_sizes, int n_in,
                              void* d_out, int out_size, void* d_ws, size_t ws_size,
                              hipStream_t stream) {
    const float* video   = (const float*)d_in[0];
    const int*   shake_h = (const int*)d_in[1];
    const int*   shake_w = (const int*)d_in[2];
    float*       out     = (float*)d_out;

    const int grid = NFRAMES * TILES_PER_FRAME;   // 10752 blocks
    shake_crop_lds16_kernel<<<grid, 256, 0, stream>>>(video, shake_h, shake_w, out);
}